// Round 16
// baseline (180.686 us; speedup 1.0000x reference)
//
#include <hip/hip_runtime.h>

#define LOG2E 1.4426950408889634f

typedef __attribute__((ext_vector_type(8))) short short8_t;    // 8 x bf16 (4 VGPRs)
typedef __attribute__((ext_vector_type(4))) float floatx4;     // 16x16 C/D frag
typedef __attribute__((ext_vector_type(16))) float floatx16;   // 32x32 C/D frag

#define MFMA(a,b,c)   __builtin_amdgcn_mfma_f32_16x16x32_bf16(a,b,c,0,0,0)
#define MFMA32(a,b,c) __builtin_amdgcn_mfma_f32_32x32x16_bf16(a,b,c,0,0,0)
#define GLOAD(g, l) __builtin_amdgcn_global_load_lds( \
    (const __attribute__((address_space(1))) unsigned int*)(g), \
    (__attribute__((address_space(3))) unsigned int*)(l), 16, 0, 0)

__device__ __forceinline__ unsigned short f2bf(float f){
    unsigned u = __float_as_uint(f);
    u = u + 0x7FFFu + ((u >> 16) & 1u);   // RNE
    return (unsigned short)(u >> 16);
}
__device__ __forceinline__ float bf2f(unsigned short s){
    return __uint_as_float(((unsigned)s) << 16);
}
// RNE pack of two floats to 2 bf16 in one uint (lo in low short)
__device__ __forceinline__ unsigned cvtpk(float lo, float hi){
    unsigned r;
    asm("v_cvt_pk_bf16_f32 %0, %1, %2" : "=v"(r) : "v"(lo), "v"(hi));
    return r;
}
// swap upper 32 lanes of a with lower 32 lanes of b (gfx950)
__device__ __forceinline__ void plswap(unsigned &a, unsigned &b){
    asm volatile("v_permlane32_swap_b32 %0, %1" : "+v"(a), "+v"(b));
}

union U8 { unsigned u[4]; short8_t s8; };

// ---------------------------------------------------------------------------
// Swizzled tile-image layouts (rule #21):
//   K/V images: 8KB tiles [64 rows][64 cols bf16],
//     off = row*64 + ((colblk ^ (row&7))<<3) + (col&7)
//   gemm A/B images: 16KB tiles [128 rows][64 cols], same per-row XOR.
// ---------------------------------------------------------------------------

// ---------------------------------------------------------------------------
// Kernel 1: per-head projections as MFMA GEMM, no LDS. (r15 verified)
// Per-sel operand orientation so all stores are ushort4/uint2:
//   sel 0/1 (Q,K): out^T = MFMA32(W,X); sel 2 (V): out = MFMA32(X,W).
// sel 0 (Q): [c][h][s][e] bf16 linear, PRE-SCALED by (1/32)*log2(e)
// sel 1 (K): [c][h][kt][8KB tile image]
// sel 2 (V): [c][h][kt][8KB tile image] of V^T
// ---------------------------------------------------------------------------
__global__ __launch_bounds__(256) void proj_kernel(
    const float* __restrict__ Xq, const float* __restrict__ Xk, const float* __restrict__ Xv,
    const float* __restrict__ Wq, const float* __restrict__ Wk, const float* __restrict__ Wv,
    unsigned short* __restrict__ qp, unsigned short* __restrict__ kp, unsigned short* __restrict__ vp)
{
    const int rt = blockIdx.x;          // 0..63 : 128-row tile
    const int h  = blockIdx.y;          // 0..15
    const int sel= blockIdx.z;          // 0,1,2
    const float* X = (sel==0)?Xq:(sel==1)?Xk:Xv;
    const float* W = (sel==0)?Wq:(sel==1)?Wk:Wv;

    const int t  = threadIdx.x;
    const int w  = t >> 6, l = t & 63;
    const int r5 = l & 31;
    const int hf = l >> 5;

    const int row0 = rt*128 + w*32;

    short8_t a[4];
    {
        const float* xb = X + (size_t)(row0 + r5)*1024 + h*64 + hf*8;
        #pragma unroll
        for (int kb=0; kb<4; kb++){
            float4 f0 = *reinterpret_cast<const float4*>(xb + kb*16);
            float4 f1 = *reinterpret_cast<const float4*>(xb + kb*16 + 4);
            U8 u;
            u.u[0] = cvtpk(f0.x, f0.y); u.u[1] = cvtpk(f0.z, f0.w);
            u.u[2] = cvtpk(f1.x, f1.y); u.u[3] = cvtpk(f1.z, f1.w);
            a[kb] = u.s8;
        }
    }
    short8_t b[2][4];
    #pragma unroll
    for (int nb=0; nb<2; nb++){
        const float* wb = W + (size_t)(nb*32 + r5)*64 + hf*8;
        #pragma unroll
        for (int kb=0; kb<4; kb++){
            float4 f0 = *reinterpret_cast<const float4*>(wb + kb*16);
            float4 f1 = *reinterpret_cast<const float4*>(wb + kb*16 + 4);
            U8 u;
            u.u[0] = cvtpk(f0.x, f0.y); u.u[1] = cvtpk(f0.z, f0.w);
            u.u[2] = cvtpk(f1.x, f1.y); u.u[3] = cvtpk(f1.z, f1.w);
            b[nb][kb] = u.s8;
        }
    }

    const int c   = rt >> 4;
    const size_t chbase = (size_t)(c*16 + h);

    floatx16 acc[2] = {};
    if (sel < 2){
        #pragma unroll
        for (int mb=0; mb<2; mb++)
            #pragma unroll
            for (int kb=0; kb<4; kb++)
                acc[mb] = MFMA32(b[mb][kb], a[kb], acc[mb]);

        const int sgl = (row0 + r5) & 2047;
        if (sel == 0){
            const float qs = (1.0f/32.0f)*LOG2E;
            unsigned short* qrow = qp + (chbase*2048 + sgl)*64;
            #pragma unroll
            for (int mb=0; mb<2; mb++)
                #pragma unroll
                for (int m=0; m<4; m++){
                    uint2 u;
                    u.x = cvtpk(acc[mb][4*m]*qs,   acc[mb][4*m+1]*qs);
                    u.y = cvtpk(acc[mb][4*m+2]*qs, acc[mb][4*m+3]*qs);
                    *reinterpret_cast<uint2*>(qrow + mb*32 + 8*m + 4*hf) = u;
                }
        } else {
            const int kt_ = sgl >> 6, rl = sgl & 63;
            unsigned short* kimg = kp + (chbase*32 + kt_)*4096 + rl*64;
            const int x7r = rl & 7;
            #pragma unroll
            for (int mb=0; mb<2; mb++)
                #pragma unroll
                for (int m=0; m<4; m++){
                    uint2 u;
                    u.x = cvtpk(acc[mb][4*m],   acc[mb][4*m+1]);
                    u.y = cvtpk(acc[mb][4*m+2], acc[mb][4*m+3]);
                    *reinterpret_cast<uint2*>(
                        kimg + (((mb*4 + m) ^ x7r)<<3) + 4*hf) = u;
                }
        }
    } else {
        #pragma unroll
        for (int nb=0; nb<2; nb++)
            #pragma unroll
            for (int kb=0; kb<4; kb++)
                acc[nb] = MFMA32(a[kb], b[nb][kb], acc[nb]);

        #pragma unroll
        for (int nb=0; nb<2; nb++){
            const int e = nb*32 + r5;
            #pragma unroll
            for (int m=0; m<4; m++){
                const int sg0 = row0 + 8*m + 4*hf;
                const int s_  = sg0 & 2047;
                const int kt_ = s_ >> 6, sl = s_ & 63;
                unsigned short* vimg = vp + (chbase*32 + kt_)*4096 + e*64;
                uint2 u;
                u.x = cvtpk(acc[nb][4*m],   acc[nb][4*m+1]);
                u.y = cvtpk(acc[nb][4*m+2], acc[nb][4*m+3]);
                *reinterpret_cast<uint2*>(
                    vimg + (((sl>>3) ^ (e&7))<<3) + (sl&7)) = u;
            }
        }
    }
}

// ---------------------------------------------------------------------------
// Kernel 2: flash attention (r11/r14 structure; r16: setprio REMOVED --
// m190-style A/B: setprio starves co-resident waves in lockstep kernels).
// ---------------------------------------------------------------------------
__global__ __launch_bounds__(256,1) void attn_kernel(
    const unsigned short* __restrict__ qp, const unsigned short* __restrict__ kp,
    const unsigned short* __restrict__ vp, unsigned short* __restrict__ ob)
{
    const int bswz = blockIdx.x;
    const int xr   = bswz & 7;
    const int rest = bswz >> 3;
    const int qt   = rest & 15;
    const int p    = xr + 8*(rest >> 4);
    const int hd   = p & 15;
    const int c    = p >> 4;

    const int t  = threadIdx.x;
    const int w  = t >> 6, l = t & 63;
    const int r5 = l & 31;
    const int hf = l >> 5;

    __shared__ unsigned short Ks[2][64][64];     // 16 KB
    __shared__ unsigned short Vs[3][64][64];     // 24 KB

    const size_t chq = ((size_t)(c*16 + hd))*2048*64;
    const size_t cht = ((size_t)(c*16 + hd))*32*4096;

    short8_t aq[4];
    {
        const unsigned short* qrow = qp + chq + (size_t)(qt*128 + w*32 + r5)*64 + hf*8;
        #pragma unroll
        for (int kb=0;kb<4;kb++)
            aq[kb] = *reinterpret_cast<const short8_t*>(qrow + kb*16);
    }

    const char* kbase = (const char*)(kp + cht) + w*2048 + l*16;
    const char* vbase = (const char*)(vp + cht) + w*2048 + l*16;
    char* kdst0 = (char*)(&Ks[0][0][0]) + w*2048;
    char* vdst0 = (char*)(&Vs[0][0][0]) + w*2048;

    #define ATTN_STAGE(kbuf, vbuf, kt) do { \
        const char* ks_ = kbase + (size_t)(kt)*8192; \
        const char* vs_ = vbase + (size_t)(kt)*8192; \
        char* kd_ = kdst0 + (kbuf)*8192; \
        char* vd_ = vdst0 + (vbuf)*8192; \
        GLOAD(ks_,      kd_);      GLOAD(ks_+1024, kd_+1024); \
        GLOAD(vs_,      vd_);      GLOAD(vs_+1024, vd_+1024); \
    } while(0)

    const int x7 = r5 & 7;

    U8 onesu;
    onesu.u[0] = 0x3F803F80u; onesu.u[1] = 0x3F803F80u;
    onesu.u[2] = 0x3F803F80u; onesu.u[3] = 0x3F803F80u;
    const short8_t ones8 = onesu.s8;

    floatx16 oa[2] = {};
    floatx16 lsv = {};
    short8_t Fp[4];

    ATTN_STAGE(0, 0, 0);

    int vcur = 0;
    for (int kt=0; kt<32; kt++){
        const int kcur = kt & 1;
        const int vnxt = (vcur==2) ? 0 : vcur+1;
        const int vprv = (vcur==0) ? 2 : vcur-1;

        asm volatile("s_waitcnt vmcnt(0)" ::: "memory");
        __builtin_amdgcn_s_barrier();
        __builtin_amdgcn_sched_barrier(0);

        if (kt < 31) ATTN_STAGE(kcur^1, vnxt, kt+1);

        const unsigned short* Kc = &Ks[kcur][0][0];
        const unsigned short* Vp = &Vs[vprv][0][0];

        floatx16 sacc[2] = {};
        #pragma unroll
        for (int mb=0;mb<2;mb++){
            #pragma unroll
            for (int kb=0;kb<4;kb++){
                short8_t kf = *reinterpret_cast<const short8_t*>(
                    Kc + (mb*32 + r5)*64 + (((kb*2 + hf) ^ x7)<<3));
                sacc[mb] = MFMA32(kf, aq[kb], sacc[mb]);
            }
        }
        if (kt > 0){
            #pragma unroll
            for (int db=0;db<2;db++){
                #pragma unroll
                for (int kb2=0;kb2<4;kb2++){
                    short8_t vf = *reinterpret_cast<const short8_t*>(
                        Vp + (db*32 + r5)*64 + (((kb2*2 + hf) ^ x7)<<3));
                    oa[db] = MFMA32(vf, Fp[kb2], oa[db]);
                }
            }
            #pragma unroll
            for (int f=0;f<4;f++) lsv = MFMA32(ones8, Fp[f], lsv);
        }

        #pragma unroll
        for (int mb=0;mb<2;mb++)
            #pragma unroll
            for (int i=0;i<16;i++)
                sacc[mb][i] = __builtin_amdgcn_exp2f(sacc[mb][i]);

        #pragma unroll
        for (int mb=0;mb<2;mb++){
            unsigned lo[4], hi[4];
            #pragma unroll
            for (int m=0;m<4;m++){
                lo[m] = cvtpk(sacc[mb][4*m],   sacc[mb][4*m+1]);
                hi[m] = cvtpk(sacc[mb][4*m+2], sacc[mb][4*m+3]);
            }
            #pragma unroll
            for (int hk=0;hk<2;hk++){
                unsigned a = lo[2*hk], b = lo[2*hk+1];
                unsigned cc = hi[2*hk], d = hi[2*hk+1];
                plswap(a, b);
                plswap(cc, d);
                U8 fu;
                fu.u[0] = a; fu.u[1] = cc; fu.u[2] = b; fu.u[3] = d;
                Fp[mb*2 + hk] = fu.s8;
            }
        }

        vcur = vnxt;
    }

    {
        const int vprv = (vcur==0) ? 2 : vcur-1;
        const unsigned short* Vp = &Vs[vprv][0][0];
        #pragma unroll
        for (int db=0;db<2;db++){
            #pragma unroll
            for (int kb2=0;kb2<4;kb2++){
                short8_t vf = *reinterpret_cast<const short8_t*>(
                    Vp + (db*32 + r5)*64 + (((kb2*2 + hf) ^ x7)<<3));
                oa[db] = MFMA32(vf, Fp[kb2], oa[db]);
            }
        }
        #pragma unroll
        for (int f=0;f<4;f++) lsv = MFMA32(ones8, Fp[f], lsv);
    }

    const float inv = 1.0f / lsv[0];
    const int rl_ = w*32 + r5;
    unsigned short* obimg = ob + ((size_t)((c*16 + qt)*16 + hd))*8192 + rl_*64;
    const int x7o = rl_ & 7;
    #pragma unroll
    for (int db=0;db<2;db++){
        #pragma unroll
        for (int m=0;m<4;m++){
            ushort4 u;
            u.x = f2bf(oa[db][4*m]*inv);   u.y = f2bf(oa[db][4*m+1]*inv);
            u.z = f2bf(oa[db][4*m+2]*inv); u.w = f2bf(oa[db][4*m+3]*inv);
            *reinterpret_cast<ushort4*>(obimg + (((db*4+m) ^ x7o)<<3) + hf*4) = u;
        }
    }
}

// ---------------------------------------------------------------------------
// Kernel 3: Wl f32 -> bf16 swizzled B-image [n>>7][k>>6][128][64-swz]
// ---------------------------------------------------------------------------
__global__ __launch_bounds__(256) void wlconv_kernel(const float* __restrict__ W,
                                                     unsigned short* __restrict__ O)
{
    int i = (blockIdx.x*256 + threadIdx.x)*4;
    const int n = i >> 10, k = i & 1023;
    float4 f = *reinterpret_cast<const float4*>(W + i);
    ushort4 u;
    u.x = f2bf(f.x); u.y = f2bf(f.y); u.z = f2bf(f.z); u.w = f2bf(f.w);
    const int rl = n & 127, cl = k & 63;
    size_t off = ((size_t)((n>>7)*16 + (k>>6)))*8192 + rl*64
               + (((cl>>3) ^ (rl&7))<<3) + (cl&7);
    *reinterpret_cast<ushort4*>(O + off) = u;
}

// ---------------------------------------------------------------------------
// Kernel 4: lin = O @ Wl^T from swizzled tile images.  BK=64,
// global_load_lds, XOR-swizzled ds_reads, counted-vmcnt dual-barrier,
// bm-colocating XCD decode.  r16: setprio REMOVED (m190 A/B).
// ---------------------------------------------------------------------------
__global__ __launch_bounds__(256) void gemm_kernel(
    const unsigned short* __restrict__ A, const unsigned short* __restrict__ B,
    unsigned short* __restrict__ C)
{
    const int wg  = blockIdx.x;
    const int xr  = wg & 7;
    const int bn  = (wg >> 3) & 7;
    const int bm  = ((wg >> 6) << 3) + xr;

    __shared__ unsigned short As[2][128][64];
    __shared__ unsigned short Bs[2][128][64];
    const int t = threadIdx.x, w = t>>6, l = t&63;
    const int l15 = l&15, l4 = l>>4;
    const int wm = w>>1, wn = w&1;
    const int x7g = l15 & 7;

    const char* abase = (const char*)A + (size_t)bm*16*16384 + w*4096 + l*16;
    const char* bbase = (const char*)B + (size_t)bn*16*16384 + w*4096 + l*16;
    char* adst = (char*)(&As[0][0][0]) + w*4096;
    char* bdst = (char*)(&Bs[0][0][0]) + w*4096;

    #define GEMM_STAGE(buf, kt) do { \
        const char* as_ = abase + (size_t)(kt)*16384; \
        const char* bs_ = bbase + (size_t)(kt)*16384; \
        char* ad_ = adst + (buf)*16384; \
        char* bd_ = bdst + (buf)*16384; \
        GLOAD(as_,       ad_);        GLOAD(as_+1024,  ad_+1024); \
        GLOAD(as_+2048,  ad_+2048);   GLOAD(as_+3072,  ad_+3072); \
        GLOAD(bs_,       bd_);        GLOAD(bs_+1024,  bd_+1024); \
        GLOAD(bs_+2048,  bd_+2048);   GLOAD(bs_+3072,  bd_+3072); \
    } while(0)

    floatx4 acc[4][4] = {};

    GEMM_STAGE(0, 0);

    for (int kt=0; kt<16; kt++){
        const int cur = kt & 1;
        if (kt < 15){
            GEMM_STAGE(cur^1, kt+1);
            asm volatile("s_waitcnt vmcnt(8)" ::: "memory");
        } else {
            asm volatile("s_waitcnt vmcnt(0)" ::: "memory");
        }
        __builtin_amdgcn_s_barrier();
        __builtin_amdgcn_sched_barrier(0);

        #pragma unroll
        for (int kk=0;kk<2;kk++){
            short8_t a[4], b[4];
            #pragma unroll
            for (int mt=0;mt<4;mt++){
                int row = wm*64 + mt*16 + l15;
                a[mt] = *reinterpret_cast<const short8_t*>(
                    &As[cur][0][0] + row*64 + (((kk*4 + l4) ^ x7g)<<3));
            }
            #pragma unroll
            for (int nt=0;nt<4;nt++){
                int row = wn*64 + nt*16 + l15;
                b[nt] = *reinterpret_cast<const short8_t*>(
                    &Bs[cur][0][0] + row*64 + (((kk*4 + l4) ^ x7g)<<3));
            }
            #pragma unroll
            for (int mt=0;mt<4;mt++)
                #pragma unroll
                for (int nt=0;nt<4;nt++)
                    acc[mt][nt] = MFMA(a[mt], b[nt], acc[mt][nt]);
        }

        __builtin_amdgcn_sched_barrier(0);
        __builtin_amdgcn_s_barrier();
    }

    #pragma unroll
    for (int mt=0;mt<4;mt++)
        #pragma unroll
        for (int nt=0;nt<4;nt++)
            #pragma unroll
            for (int j=0;j<4;j++){
                int row = bm*128 + wm*64 + mt*16 + l4*4 + j;
                int col = bn*128 + wn*64 + nt*16 + l15;
                C[(size_t)row*1024 + col] = f2bf(acc[mt][nt][j]);
            }
}

// ---------------------------------------------------------------------------
// Kernel 5: LayerNorm + residual. (at its HBM roofline)
// ---------------------------------------------------------------------------
__global__ __launch_bounds__(256) void ln_kernel(
    const unsigned short* __restrict__ lin, const float* __restrict__ qin,
    const float* __restrict__ gamma, const float* __restrict__ beta, float* __restrict__ out)
{
    const int r = blockIdx.x, t = threadIdx.x;
    const unsigned short* row = lin + (size_t)r*1024;
    uint2 u = *reinterpret_cast<const uint2*>(row + t*4);
    float v0 = bf2f((unsigned short)(u.x & 0xffffu));
    float v1 = bf2f((unsigned short)(u.x >> 16));
    float v2 = bf2f((unsigned short)(u.y & 0xffffu));
    float v3 = bf2f((unsigned short)(u.y >> 16));
    float s  = v0+v1+v2+v3;
    float sq = v0*v0+v1*v1+v2*v2+v3*v3;
    #pragma unroll
    for (int d=1; d<64; d<<=1){ s += __shfl_xor(s, d); sq += __shfl_xor(sq, d); }
    __shared__ float red[8];
    if ((t&63)==0){ red[(t>>6)*2] = s; red[(t>>6)*2+1] = sq; }
    __syncthreads();
    s  = red[0]+red[2]+red[4]+red[6];
    sq = red[1]+red[3]+red[5]+red[7];
    float mean = s*(1.f/1024.f);
    float var  = sq*(1.f/1024.f) - mean*mean;
    float rs   = rsqrtf(var + 1e-5f);
    int base = r*1024 + t*4;
    float4 qv = *reinterpret_cast<const float4*>(qin + base);
    float4 g  = *reinterpret_cast<const float4*>(gamma + t*4);
    float4 b  = *reinterpret_cast<const float4*>(beta + t*4);
    float4 o;
    o.x = qv.x + (v0-mean)*rs*g.x + b.x;
    o.y = qv.y + (v1-mean)*rs*g.y + b.y;
    o.z = qv.z + (v2-mean)*rs*g.z + b.z;
    o.w = qv.w + (v3-mean)*rs*g.w + b.w;
    *reinterpret_cast<float4*>(out + base) = o;
}

// ---------------------------------------------------------------------------
extern "C" void kernel_launch(void* const* d_in, const int* in_sizes, int n_in,
                              void* d_out, int out_size, void* d_ws, size_t ws_size,
                              hipStream_t stream)
{
    (void)in_sizes; (void)n_in; (void)out_size; (void)ws_size;
    const float* q     = (const float*)d_in[0];
    const float* k     = (const float*)d_in[1];
    const float* v     = (const float*)d_in[2];
    const float* Wq    = (const float*)d_in[3];
    const float* Wk    = (const float*)d_in[4];
    const float* Wv    = (const float*)d_in[5];
    const float* Wl    = (const float*)d_in[6];
    const float* gamma = (const float*)d_in[7];
    const float* beta  = (const float*)d_in[8];
    float* out = (float*)d_out;

    char* ws = (char*)d_ws;
    unsigned short* qp  = (unsigned short*)(ws);                 // 16 MB [c][h][s][e] (pre-scaled)
    unsigned short* kp  = (unsigned short*)(ws + (16u<<20));     // 16 MB K tile images
    unsigned short* vp  = (unsigned short*)(ws + (32u<<20));     // 16 MB V^T tile images
    unsigned short* ob  = (unsigned short*)(ws + (48u<<20));     // 16 MB A tile images
    unsigned short* lin = (unsigned short*)(ws);                 // reuse qp (dead after attn)
    unsigned short* wlb = (unsigned short*)(ws + (16u<<20));     // reuse kp: B tile images

    proj_kernel <<<dim3(64,16,3),  256, 0, stream>>>(q,k,v, Wq,Wk,Wv, qp,kp,vp);
    attn_kernel <<<dim3(1024),     256, 0, stream>>>(qp,kp,vp, ob);
    wlconv_kernel<<<dim3(1024),    256, 0, stream>>>(Wl, wlb);
    gemm_kernel <<<dim3(512),      256, 0, stream>>>(ob, wlb, lin);
    ln_kernel   <<<dim3(8192),     256, 0, stream>>>(lin, q, gamma, beta, out);
}

// Round 17
// 168.596 us; speedup vs baseline: 1.0717x; 1.0717x over previous
//
#include <hip/hip_runtime.h>

#define LOG2E 1.4426950408889634f

typedef __attribute__((ext_vector_type(8))) short short8_t;    // 8 x bf16 (4 VGPRs)
typedef __attribute__((ext_vector_type(4))) float floatx4;     // 16x16 C/D frag
typedef __attribute__((ext_vector_type(16))) float floatx16;   // 32x32 C/D frag

#define MFMA(a,b,c)   __builtin_amdgcn_mfma_f32_16x16x32_bf16(a,b,c,0,0,0)
#define MFMA32(a,b,c) __builtin_amdgcn_mfma_f32_32x32x16_bf16(a,b,c,0,0,0)
#define GLOAD(g, l) __builtin_amdgcn_global_load_lds( \
    (const __attribute__((address_space(1))) unsigned int*)(g), \
    (__attribute__((address_space(3))) unsigned int*)(l), 16, 0, 0)

__device__ __forceinline__ unsigned short f2bf(float f){
    unsigned u = __float_as_uint(f);
    u = u + 0x7FFFu + ((u >> 16) & 1u);   // RNE
    return (unsigned short)(u >> 16);
}
__device__ __forceinline__ float bf2f(unsigned short s){
    return __uint_as_float(((unsigned)s) << 16);
}
// RNE pack of two floats to 2 bf16 in one uint (lo in low short)
__device__ __forceinline__ unsigned cvtpk(float lo, float hi){
    unsigned r;
    asm("v_cvt_pk_bf16_f32 %0, %1, %2" : "=v"(r) : "v"(lo), "v"(hi));
    return r;
}
// swap upper 32 lanes of a with lower 32 lanes of b (gfx950)
__device__ __forceinline__ void plswap(unsigned &a, unsigned &b){
    asm volatile("v_permlane32_swap_b32 %0, %1" : "+v"(a), "+v"(b));
}

union U8 { unsigned u[4]; short8_t s8; };

// ---------------------------------------------------------------------------
// Swizzled tile-image layouts (rule #21):
//   K/V images: 8KB tiles [64 rows][64 cols bf16],
//     off = row*64 + ((colblk ^ (row&7))<<3) + (col&7)
//   gemm A/B images: 16KB tiles [128 rows][64 cols], same per-row XOR.
// ---------------------------------------------------------------------------

// ---------------------------------------------------------------------------
// Kernel 1: per-head projections as MFMA GEMM, no LDS. (r15 verified)
// Per-sel operand orientation so all stores are ushort4/uint2:
//   sel 0/1 (Q,K): out^T = MFMA32(W,X); sel 2 (V): out = MFMA32(X,W).
// sel 0 (Q): [c][h][s][e] bf16 linear, PRE-SCALED by (1/32)*log2(e)
// sel 1 (K): [c][h][kt][8KB tile image]
// sel 2 (V): [c][h][kt][8KB tile image] of V^T
// ---------------------------------------------------------------------------
__global__ __launch_bounds__(256) void proj_kernel(
    const float* __restrict__ Xq, const float* __restrict__ Xk, const float* __restrict__ Xv,
    const float* __restrict__ Wq, const float* __restrict__ Wk, const float* __restrict__ Wv,
    unsigned short* __restrict__ qp, unsigned short* __restrict__ kp, unsigned short* __restrict__ vp)
{
    const int rt = blockIdx.x;          // 0..63 : 128-row tile
    const int h  = blockIdx.y;          // 0..15
    const int sel= blockIdx.z;          // 0,1,2
    const float* X = (sel==0)?Xq:(sel==1)?Xk:Xv;
    const float* W = (sel==0)?Wq:(sel==1)?Wk:Wv;

    const int t  = threadIdx.x;
    const int w  = t >> 6, l = t & 63;
    const int r5 = l & 31;
    const int hf = l >> 5;

    const int row0 = rt*128 + w*32;

    short8_t a[4];
    {
        const float* xb = X + (size_t)(row0 + r5)*1024 + h*64 + hf*8;
        #pragma unroll
        for (int kb=0; kb<4; kb++){
            float4 f0 = *reinterpret_cast<const float4*>(xb + kb*16);
            float4 f1 = *reinterpret_cast<const float4*>(xb + kb*16 + 4);
            U8 u;
            u.u[0] = cvtpk(f0.x, f0.y); u.u[1] = cvtpk(f0.z, f0.w);
            u.u[2] = cvtpk(f1.x, f1.y); u.u[3] = cvtpk(f1.z, f1.w);
            a[kb] = u.s8;
        }
    }
    short8_t b[2][4];
    #pragma unroll
    for (int nb=0; nb<2; nb++){
        const float* wb = W + (size_t)(nb*32 + r5)*64 + hf*8;
        #pragma unroll
        for (int kb=0; kb<4; kb++){
            float4 f0 = *reinterpret_cast<const float4*>(wb + kb*16);
            float4 f1 = *reinterpret_cast<const float4*>(wb + kb*16 + 4);
            U8 u;
            u.u[0] = cvtpk(f0.x, f0.y); u.u[1] = cvtpk(f0.z, f0.w);
            u.u[2] = cvtpk(f1.x, f1.y); u.u[3] = cvtpk(f1.z, f1.w);
            b[nb][kb] = u.s8;
        }
    }

    const int c   = rt >> 4;
    const size_t chbase = (size_t)(c*16 + h);

    floatx16 acc[2] = {};
    if (sel < 2){
        // swapped: D rows = e (regs), cols = s (lane r5)
        #pragma unroll
        for (int mb=0; mb<2; mb++)
            #pragma unroll
            for (int kb=0; kb<4; kb++)
                acc[mb] = MFMA32(b[mb][kb], a[kb], acc[mb]);

        const int sgl = (row0 + r5) & 2047;       // seq row within chunk
        if (sel == 0){
            const float qs = (1.0f/32.0f)*LOG2E;
            unsigned short* qrow = qp + (chbase*2048 + sgl)*64;
            #pragma unroll
            for (int mb=0; mb<2; mb++)
                #pragma unroll
                for (int m=0; m<4; m++){
                    uint2 u;
                    u.x = cvtpk(acc[mb][4*m]*qs,   acc[mb][4*m+1]*qs);
                    u.y = cvtpk(acc[mb][4*m+2]*qs, acc[mb][4*m+3]*qs);
                    *reinterpret_cast<uint2*>(qrow + mb*32 + 8*m + 4*hf) = u;
                }
        } else {
            const int kt_ = sgl >> 6, rl = sgl & 63;
            unsigned short* kimg = kp + (chbase*32 + kt_)*4096 + rl*64;
            const int x7r = rl & 7;
            #pragma unroll
            for (int mb=0; mb<2; mb++)
                #pragma unroll
                for (int m=0; m<4; m++){
                    uint2 u;
                    u.x = cvtpk(acc[mb][4*m],   acc[mb][4*m+1]);
                    u.y = cvtpk(acc[mb][4*m+2], acc[mb][4*m+3]);
                    *reinterpret_cast<uint2*>(
                        kimg + (((mb*4 + m) ^ x7r)<<3) + 4*hf) = u;
                }
        }
    } else {
        // V: D rows = s (regs), cols = d (lane r5)
        #pragma unroll
        for (int nb=0; nb<2; nb++)
            #pragma unroll
            for (int kb=0; kb<4; kb++)
                acc[nb] = MFMA32(a[kb], b[nb][kb], acc[nb]);

        #pragma unroll
        for (int nb=0; nb<2; nb++){
            const int e = nb*32 + r5;             // dim d
            #pragma unroll
            for (int m=0; m<4; m++){
                const int sg0 = row0 + 8*m + 4*hf;        // + i (0..3)
                const int s_  = sg0 & 2047;
                const int kt_ = s_ >> 6, sl = s_ & 63;
                unsigned short* vimg = vp + (chbase*32 + kt_)*4096 + e*64;
                uint2 u;
                u.x = cvtpk(acc[nb][4*m],   acc[nb][4*m+1]);
                u.y = cvtpk(acc[nb][4*m+2], acc[nb][4*m+3]);
                *reinterpret_cast<uint2*>(
                    vimg + (((sl>>3) ^ (e&7))<<3) + (sl&7)) = u;
            }
        }
    }
}

// ---------------------------------------------------------------------------
// Kernel 2: flash attention (r11/r14/r15's verified kernel, byte-for-byte;
// setprio RESTORED -- r16 A/B measured removing it costs 14.5us: co-resident
// blocks are phase-independent, so the MFMA-priority hint pays as in m191).
// ---------------------------------------------------------------------------
__global__ __launch_bounds__(256,1) void attn_kernel(
    const unsigned short* __restrict__ qp, const unsigned short* __restrict__ kp,
    const unsigned short* __restrict__ vp, unsigned short* __restrict__ ob)
{
    const int bswz = blockIdx.x;
    const int xr   = bswz & 7;
    const int rest = bswz >> 3;
    const int qt   = rest & 15;
    const int p    = xr + 8*(rest >> 4);
    const int hd   = p & 15;
    const int c    = p >> 4;

    const int t  = threadIdx.x;
    const int w  = t >> 6, l = t & 63;
    const int r5 = l & 31;
    const int hf = l >> 5;

    __shared__ unsigned short Ks[2][64][64];     // 16 KB
    __shared__ unsigned short Vs[3][64][64];     // 24 KB

    const size_t chq = ((size_t)(c*16 + hd))*2048*64;
    const size_t cht = ((size_t)(c*16 + hd))*32*4096;

    short8_t aq[4];
    {
        const unsigned short* qrow = qp + chq + (size_t)(qt*128 + w*32 + r5)*64 + hf*8;
        #pragma unroll
        for (int kb=0;kb<4;kb++)
            aq[kb] = *reinterpret_cast<const short8_t*>(qrow + kb*16);
    }

    const char* kbase = (const char*)(kp + cht) + w*2048 + l*16;
    const char* vbase = (const char*)(vp + cht) + w*2048 + l*16;
    char* kdst0 = (char*)(&Ks[0][0][0]) + w*2048;
    char* vdst0 = (char*)(&Vs[0][0][0]) + w*2048;

    #define ATTN_STAGE(kbuf, vbuf, kt) do { \
        const char* ks_ = kbase + (size_t)(kt)*8192; \
        const char* vs_ = vbase + (size_t)(kt)*8192; \
        char* kd_ = kdst0 + (kbuf)*8192; \
        char* vd_ = vdst0 + (vbuf)*8192; \
        GLOAD(ks_,      kd_);      GLOAD(ks_+1024, kd_+1024); \
        GLOAD(vs_,      vd_);      GLOAD(vs_+1024, vd_+1024); \
    } while(0)

    const int x7 = r5 & 7;

    U8 onesu;
    onesu.u[0] = 0x3F803F80u; onesu.u[1] = 0x3F803F80u;
    onesu.u[2] = 0x3F803F80u; onesu.u[3] = 0x3F803F80u;
    const short8_t ones8 = onesu.s8;

    floatx16 oa[2] = {};
    floatx16 lsv = {};
    short8_t Fp[4];

    ATTN_STAGE(0, 0, 0);

    int vcur = 0;
    for (int kt=0; kt<32; kt++){
        const int kcur = kt & 1;
        const int vnxt = (vcur==2) ? 0 : vcur+1;
        const int vprv = (vcur==0) ? 2 : vcur-1;

        asm volatile("s_waitcnt vmcnt(0)" ::: "memory");
        __builtin_amdgcn_s_barrier();
        __builtin_amdgcn_sched_barrier(0);

        if (kt < 31) ATTN_STAGE(kcur^1, vnxt, kt+1);

        const unsigned short* Kc = &Ks[kcur][0][0];
        const unsigned short* Vp = &Vs[vprv][0][0];

        floatx16 sacc[2] = {};
        __builtin_amdgcn_s_setprio(1);
        #pragma unroll
        for (int mb=0;mb<2;mb++){
            #pragma unroll
            for (int kb=0;kb<4;kb++){
                short8_t kf = *reinterpret_cast<const short8_t*>(
                    Kc + (mb*32 + r5)*64 + (((kb*2 + hf) ^ x7)<<3));
                sacc[mb] = MFMA32(kf, aq[kb], sacc[mb]);
            }
        }
        if (kt > 0){
            #pragma unroll
            for (int db=0;db<2;db++){
                #pragma unroll
                for (int kb2=0;kb2<4;kb2++){
                    short8_t vf = *reinterpret_cast<const short8_t*>(
                        Vp + (db*32 + r5)*64 + (((kb2*2 + hf) ^ x7)<<3));
                    oa[db] = MFMA32(vf, Fp[kb2], oa[db]);
                }
            }
            #pragma unroll
            for (int f=0;f<4;f++) lsv = MFMA32(ones8, Fp[f], lsv);
        }
        __builtin_amdgcn_s_setprio(0);

        #pragma unroll
        for (int mb=0;mb<2;mb++)
            #pragma unroll
            for (int i=0;i<16;i++)
                sacc[mb][i] = __builtin_amdgcn_exp2f(sacc[mb][i]);

        #pragma unroll
        for (int mb=0;mb<2;mb++){
            unsigned lo[4], hi[4];
            #pragma unroll
            for (int m=0;m<4;m++){
                lo[m] = cvtpk(sacc[mb][4*m],   sacc[mb][4*m+1]);
                hi[m] = cvtpk(sacc[mb][4*m+2], sacc[mb][4*m+3]);
            }
            #pragma unroll
            for (int hk=0;hk<2;hk++){
                unsigned a = lo[2*hk], b = lo[2*hk+1];
                unsigned cc = hi[2*hk], d = hi[2*hk+1];
                plswap(a, b);
                plswap(cc, d);
                U8 fu;
                fu.u[0] = a; fu.u[1] = cc; fu.u[2] = b; fu.u[3] = d;
                Fp[mb*2 + hk] = fu.s8;
            }
        }

        vcur = vnxt;
    }

    {
        const int vprv = (vcur==0) ? 2 : vcur-1;
        const unsigned short* Vp = &Vs[vprv][0][0];
        #pragma unroll
        for (int db=0;db<2;db++){
            #pragma unroll
            for (int kb2=0;kb2<4;kb2++){
                short8_t vf = *reinterpret_cast<const short8_t*>(
                    Vp + (db*32 + r5)*64 + (((kb2*2 + hf) ^ x7)<<3));
                oa[db] = MFMA32(vf, Fp[kb2], oa[db]);
            }
        }
        #pragma unroll
        for (int f=0;f<4;f++) lsv = MFMA32(ones8, Fp[f], lsv);
    }

    const float inv = 1.0f / lsv[0];
    const int rl_ = w*32 + r5;
    unsigned short* obimg = ob + ((size_t)((c*16 + qt)*16 + hd))*8192 + rl_*64;
    const int x7o = rl_ & 7;
    #pragma unroll
    for (int db=0;db<2;db++){
        #pragma unroll
        for (int m=0;m<4;m++){
            ushort4 u;
            u.x = f2bf(oa[db][4*m]*inv);   u.y = f2bf(oa[db][4*m+1]*inv);
            u.z = f2bf(oa[db][4*m+2]*inv); u.w = f2bf(oa[db][4*m+3]*inv);
            *reinterpret_cast<ushort4*>(obimg + (((db*4+m) ^ x7o)<<3) + hf*4) = u;
        }
    }
}

// ---------------------------------------------------------------------------
// Kernel 3: Wl f32 -> bf16 swizzled B-image [n>>7][k>>6][128][64-swz]
// ---------------------------------------------------------------------------
__global__ __launch_bounds__(256) void wlconv_kernel(const float* __restrict__ W,
                                                     unsigned short* __restrict__ O)
{
    int i = (blockIdx.x*256 + threadIdx.x)*4;
    const int n = i >> 10, k = i & 1023;
    float4 f = *reinterpret_cast<const float4*>(W + i);
    ushort4 u;
    u.x = f2bf(f.x); u.y = f2bf(f.y); u.z = f2bf(f.z); u.w = f2bf(f.w);
    const int rl = n & 127, cl = k & 63;
    size_t off = ((size_t)((n>>7)*16 + (k>>6)))*8192 + rl*64
               + (((cl>>3) ^ (rl&7))<<3) + (cl&7);
    *reinterpret_cast<ushort4*>(O + off) = u;
}

// ---------------------------------------------------------------------------
// Kernel 4: lin = O @ Wl^T from swizzled tile images.  BK=64,
// global_load_lds, XOR-swizzled ds_reads, counted-vmcnt dual-barrier,
// bm-colocating XCD decode, setprio restored. (r15 verified)
// ---------------------------------------------------------------------------
__global__ __launch_bounds__(256) void gemm_kernel(
    const unsigned short* __restrict__ A, const unsigned short* __restrict__ B,
    unsigned short* __restrict__ C)
{
    const int wg  = blockIdx.x;
    const int xr  = wg & 7;
    const int bn  = (wg >> 3) & 7;
    const int bm  = ((wg >> 6) << 3) + xr;

    __shared__ unsigned short As[2][128][64];
    __shared__ unsigned short Bs[2][128][64];
    const int t = threadIdx.x, w = t>>6, l = t&63;
    const int l15 = l&15, l4 = l>>4;
    const int wm = w>>1, wn = w&1;
    const int x7g = l15 & 7;

    const char* abase = (const char*)A + (size_t)bm*16*16384 + w*4096 + l*16;
    const char* bbase = (const char*)B + (size_t)bn*16*16384 + w*4096 + l*16;
    char* adst = (char*)(&As[0][0][0]) + w*4096;
    char* bdst = (char*)(&Bs[0][0][0]) + w*4096;

    #define GEMM_STAGE(buf, kt) do { \
        const char* as_ = abase + (size_t)(kt)*16384; \
        const char* bs_ = bbase + (size_t)(kt)*16384; \
        char* ad_ = adst + (buf)*16384; \
        char* bd_ = bdst + (buf)*16384; \
        GLOAD(as_,       ad_);        GLOAD(as_+1024,  ad_+1024); \
        GLOAD(as_+2048,  ad_+2048);   GLOAD(as_+3072,  ad_+3072); \
        GLOAD(bs_,       bd_);        GLOAD(bs_+1024,  bd_+1024); \
        GLOAD(bs_+2048,  bd_+2048);   GLOAD(bs_+3072,  bd_+3072); \
    } while(0)

    floatx4 acc[4][4] = {};

    GEMM_STAGE(0, 0);

    for (int kt=0; kt<16; kt++){
        const int cur = kt & 1;
        if (kt < 15){
            GEMM_STAGE(cur^1, kt+1);
            asm volatile("s_waitcnt vmcnt(8)" ::: "memory");
        } else {
            asm volatile("s_waitcnt vmcnt(0)" ::: "memory");
        }
        __builtin_amdgcn_s_barrier();
        __builtin_amdgcn_sched_barrier(0);

        #pragma unroll
        for (int kk=0;kk<2;kk++){
            short8_t a[4], b[4];
            #pragma unroll
            for (int mt=0;mt<4;mt++){
                int row = wm*64 + mt*16 + l15;
                a[mt] = *reinterpret_cast<const short8_t*>(
                    &As[cur][0][0] + row*64 + (((kk*4 + l4) ^ x7g)<<3));
            }
            #pragma unroll
            for (int nt=0;nt<4;nt++){
                int row = wn*64 + nt*16 + l15;
                b[nt] = *reinterpret_cast<const short8_t*>(
                    &Bs[cur][0][0] + row*64 + (((kk*4 + l4) ^ x7g)<<3));
            }
            __builtin_amdgcn_s_setprio(1);
            #pragma unroll
            for (int mt=0;mt<4;mt++)
                #pragma unroll
                for (int nt=0;nt<4;nt++)
                    acc[mt][nt] = MFMA(a[mt], b[nt], acc[mt][nt]);
            __builtin_amdgcn_s_setprio(0);
        }

        __builtin_amdgcn_sched_barrier(0);
        __builtin_amdgcn_s_barrier();
    }

    #pragma unroll
    for (int mt=0;mt<4;mt++)
        #pragma unroll
        for (int nt=0;nt<4;nt++)
            #pragma unroll
            for (int j=0;j<4;j++){
                int row = bm*128 + wm*64 + mt*16 + l4*4 + j;
                int col = bn*128 + wn*64 + nt*16 + l15;
                C[(size_t)row*1024 + col] = f2bf(acc[mt][nt][j]);
            }
}

// ---------------------------------------------------------------------------
// Kernel 5: LayerNorm + residual. (at its HBM roofline)
// ---------------------------------------------------------------------------
__global__ __launch_bounds__(256) void ln_kernel(
    const unsigned short* __restrict__ lin, const float* __restrict__ qin,
    const float* __restrict__ gamma, const float* __restrict__ beta, float* __restrict__ out)
{
    const int r = blockIdx.x, t = threadIdx.x;
    const unsigned short* row = lin + (size_t)r*1024;
    uint2 u = *reinterpret_cast<const uint2*>(row + t*4);
    float v0 = bf2f((unsigned short)(u.x & 0xffffu));
    float v1 = bf2f((unsigned short)(u.x >> 16));
    float v2 = bf2f((unsigned short)(u.y & 0xffffu));
    float v3 = bf2f((unsigned short)(u.y >> 16));
    float s  = v0+v1+v2+v3;
    float sq = v0*v0+v1*v1+v2*v2+v3*v3;
    #pragma unroll
    for (int d=1; d<64; d<<=1){ s += __shfl_xor(s, d); sq += __shfl_xor(sq, d); }
    __shared__ float red[8];
    if ((t&63)==0){ red[(t>>6)*2] = s; red[(t>>6)*2+1] = sq; }
    __syncthreads();
    s  = red[0]+red[2]+red[4]+red[6];
    sq = red[1]+red[3]+red[5]+red[7];
    float mean = s*(1.f/1024.f);
    float var  = sq*(1.f/1024.f) - mean*mean;
    float rs   = rsqrtf(var + 1e-5f);
    int base = r*1024 + t*4;
    float4 qv = *reinterpret_cast<const float4*>(qin + base);
    float4 g  = *reinterpret_cast<const float4*>(gamma + t*4);
    float4 b  = *reinterpret_cast<const float4*>(beta + t*4);
    float4 o;
    o.x = qv.x + (v0-mean)*rs*g.x + b.x;
    o.y = qv.y + (v1-mean)*rs*g.y + b.y;
    o.z = qv.z + (v2-mean)*rs*g.z + b.z;
    o.w = qv.w + (v3-mean)*rs*g.w + b.w;
    *reinterpret_cast<float4*>(out + base) = o;
}

// ---------------------------------------------------------------------------
extern "C" void kernel_launch(void* const* d_in, const int* in_sizes, int n_in,
                              void* d_out, int out_size, void* d_ws, size_t ws_size,
                              hipStream_t stream)
{
    (void)in_sizes; (void)n_in; (void)out_size; (void)ws_size;
    const float* q     = (const float*)d_in[0];
    const float* k     = (const float*)d_in[1];
    const float* v     = (const float*)d_in[2];
    const float* Wq    = (const float*)d_in[3];
    const float* Wk    = (const float*)d_in[4];
    const float* Wv    = (const float*)d_in[5];
    const float* Wl    = (const float*)d_in[6];
    const float* gamma = (const float*)d_in[7];
    const float* beta  = (const float*)d_in[8];
    float* out = (float*)d_out;

    char* ws = (char*)d_ws;
    unsigned short* qp  = (unsigned short*)(ws);                 // 16 MB [c][h][s][e] (pre-scaled)
    unsigned short* kp  = (unsigned short*)(ws + (16u<<20));     // 16 MB K tile images
    unsigned short* vp  = (unsigned short*)(ws + (32u<<20));     // 16 MB V^T tile images
    unsigned short* ob  = (unsigned short*)(ws + (48u<<20));     // 16 MB A tile images
    unsigned short* lin = (unsigned short*)(ws);                 // reuse qp (dead after attn)
    unsigned short* wlb = (unsigned short*)(ws + (16u<<20));     // reuse kp: B tile images

    proj_kernel <<<dim3(64,16,3),  256, 0, stream>>>(q,k,v, Wq,Wk,Wv, qp,kp,vp);
    attn_kernel <<<dim3(1024),     256, 0, stream>>>(qp,kp,vp, ob);
    wlconv_kernel<<<dim3(1024),    256, 0, stream>>>(Wl, wlb);
    gemm_kernel <<<dim3(512),      256, 0, stream>>>(ob, wlb, lin);
    ln_kernel   <<<dim3(8192),     256, 0, stream>>>(lin, q, gamma, beta, out);
}